// Round 13
// baseline (10785.783 us; speedup 1.0000x reference)
//
#include <hip/hip_runtime.h>
#include <hip/hip_bf16.h>
#include <float.h>

#define KDIM 512
#define MBLK 64
#define NBLK 256
#define KBLK 32
#define NTH  256
#define APAD 68
#define BPAD 260
#define TOPK 8

// f32 whose high 16 bits are the RNE bf16 of v: harness's bf16 view of our
// f32 slot then equals RNE_bf16(v), matching the reference's quantization.
__device__ __forceinline__ float bf16_rne_f32(float v) {
  return __bfloat162float(__float2bfloat16(v));
}

// ---- row L2 norms in EXACT numpy pairwise order ---------------------------
// np.sum(x*x, axis=1) for n=512: pairwise -> (B0+B1)+(B2+B3), each B a
// 128-block with 8 strided accumulators r[j]=sum(x2[8i+j]) combined
// ((r0+r1)+(r2+r3))+((r4+r5)+(r6+r7)). All ops RNE, no FMA contraction.
__global__ void er_norms(const float* __restrict__ T, const float* __restrict__ S,
                         float* __restrict__ nt, float* __restrict__ ns,
                         int M, int N) {
  int gid = blockIdx.x * blockDim.x + threadIdx.x;
  int row = gid >> 2;            // 4 lanes per row, one per 128-block
  int b   = gid & 3;
  if (row >= M + N) return;
  const float* base = (row < M) ? (T + (size_t)row * KDIM)
                                : (S + (size_t)(row - M) * KDIM);
  const float4* p4 = (const float4*)(base + b * 128);
  float r[8];
  {
    float4 f0 = p4[0], f1 = p4[1];
    r[0] = __fmul_rn(f0.x, f0.x); r[1] = __fmul_rn(f0.y, f0.y);
    r[2] = __fmul_rn(f0.z, f0.z); r[3] = __fmul_rn(f0.w, f0.w);
    r[4] = __fmul_rn(f1.x, f1.x); r[5] = __fmul_rn(f1.y, f1.y);
    r[6] = __fmul_rn(f1.z, f1.z); r[7] = __fmul_rn(f1.w, f1.w);
  }
  #pragma unroll
  for (int i = 2; i < 32; i += 2) {
    float4 f0 = p4[i], f1 = p4[i + 1];
    r[0] = __fadd_rn(r[0], __fmul_rn(f0.x, f0.x));
    r[1] = __fadd_rn(r[1], __fmul_rn(f0.y, f0.y));
    r[2] = __fadd_rn(r[2], __fmul_rn(f0.z, f0.z));
    r[3] = __fadd_rn(r[3], __fmul_rn(f0.w, f0.w));
    r[4] = __fadd_rn(r[4], __fmul_rn(f1.x, f1.x));
    r[5] = __fadd_rn(r[5], __fmul_rn(f1.y, f1.y));
    r[6] = __fadd_rn(r[6], __fmul_rn(f1.z, f1.z));
    r[7] = __fadd_rn(r[7], __fmul_rn(f1.w, f1.w));
  }
  float B = __fadd_rn(__fadd_rn(__fadd_rn(r[0], r[1]), __fadd_rn(r[2], r[3])),
                      __fadd_rn(__fadd_rn(r[4], r[5]), __fadd_rn(r[6], r[7])));
  // combine 4 blocks: (B0+B1)+(B2+B3)  (f32 add is commutative bitwise)
  float t = __fadd_rn(B, __shfl_xor(B, 1, 64));
  float s = __fadd_rn(t, __shfl_xor(t, 2, 64));
  if (b == 0) {
    float nr = __fsqrt_rn(s);
    if (row < M) nt[row] = nr; else ns[row - M] = nr;
  }
}

// ---- fused: normalized-f32 GEMM (BLAS-order) + top-8 + softmax + store ----
__global__ __launch_bounds__(NTH, 1)
void er_fused(const float* __restrict__ A, const float* __restrict__ B,
              const float* __restrict__ imp,
              const float* __restrict__ nt, const float* __restrict__ ns,
              float* __restrict__ out, int M, int N) {
  __shared__ float a_lds[KBLK][APAD];
  __shared__ float b_lds[KBLK][BPAD];
  __shared__ float tval[MBLK][TOPK];
  __shared__ int   tidx[MBLK][TOPK];
  __shared__ float tthr[MBLK];

  const int tid    = threadIdx.x;
  const int m_base = blockIdx.x * MBLK;
  const int tm = tid >> 5;        // rows tm*8..tm*8+7 (wave-exclusive rows)
  const int tn = tid & 31;        // cols tn*8..tn*8+7
  const int lane = tid & 63;
  const int ntiles = N / NBLK;

  if (tid < MBLK) {
    tthr[tid] = -FLT_MAX;
    #pragma unroll
    for (int j = 0; j < TOPK; ++j) { tval[tid][j] = -FLT_MAX; tidx[tid][j] = 0; }
  }
  __syncthreads();

  #pragma unroll 1
  for (int t = 0; t < ntiles; ++t) {
    const int n_base = t * NBLK;
    float acc[8][8];
    #pragma unroll
    for (int i = 0; i < 8; ++i)
      #pragma unroll
      for (int j = 0; j < 8; ++j) acc[i][j] = 0.f;

    float4 ar[2], br[8];
    #pragma unroll
    for (int ii = 0; ii < 2; ++ii) {
      int u = tid + NTH * ii, row = u >> 3, ks = u & 7;
      ar[ii] = *(const float4*)&A[(size_t)(m_base + row) * KDIM + ks * 4];
    }
    #pragma unroll
    for (int ii = 0; ii < 8; ++ii) {
      int u = tid + NTH * ii, row = u >> 3, ks = u & 7;
      br[ii] = *(const float4*)&B[(size_t)(n_base + row) * KDIM + ks * 4];
    }

    #pragma unroll 1
    for (int kc = 0; kc < KDIM / KBLK; ++kc) {
      __syncthreads();
      #pragma unroll
      for (int ii = 0; ii < 2; ++ii) {   // stage normalized: x / max(||row||,eps)
        int u = tid + NTH * ii, row = u >> 3, ks = u & 7;
        float dn = fmaxf(nt[m_base + row], 1e-12f);
        a_lds[ks*4+0][row] = __fdiv_rn(ar[ii].x, dn);
        a_lds[ks*4+1][row] = __fdiv_rn(ar[ii].y, dn);
        a_lds[ks*4+2][row] = __fdiv_rn(ar[ii].z, dn);
        a_lds[ks*4+3][row] = __fdiv_rn(ar[ii].w, dn);
      }
      #pragma unroll
      for (int ii = 0; ii < 8; ++ii) {
        int u = tid + NTH * ii, row = u >> 3, ks = u & 7;
        float dn = fmaxf(ns[n_base + row], 1e-12f);
        b_lds[ks*4+0][row] = __fdiv_rn(br[ii].x, dn);
        b_lds[ks*4+1][row] = __fdiv_rn(br[ii].y, dn);
        b_lds[ks*4+2][row] = __fdiv_rn(br[ii].z, dn);
        b_lds[ks*4+3][row] = __fdiv_rn(br[ii].w, dn);
      }
      __syncthreads();
      if (kc + 1 < KDIM / KBLK) {
        int kb = (kc + 1) * KBLK;
        #pragma unroll
        for (int ii = 0; ii < 2; ++ii) {
          int u = tid + NTH * ii, row = u >> 3, ks = u & 7;
          ar[ii] = *(const float4*)&A[(size_t)(m_base + row) * KDIM + kb + ks * 4];
        }
        #pragma unroll
        for (int ii = 0; ii < 8; ++ii) {
          int u = tid + NTH * ii, row = u >> 3, ks = u & 7;
          br[ii] = *(const float4*)&B[(size_t)(n_base + row) * KDIM + kb + ks * 4];
        }
      }
      // sequential-k FMA chain (BLAS microkernel order), k ascending
      #pragma unroll 8
      for (int k = 0; k < KBLK; ++k) {
        const float4* ap = (const float4*)&a_lds[k][tm * 8];
        const float4* bp = (const float4*)&b_lds[k][tn * 8];
        float4 a0 = ap[0], a1 = ap[1], b0 = bp[0], b1 = bp[1];
        float av[8] = {a0.x,a0.y,a0.z,a0.w,a1.x,a1.y,a1.z,a1.w};
        float bw[8] = {b0.x,b0.y,b0.z,b0.w,b1.x,b1.y,b1.z,b1.w};
        #pragma unroll
        for (int i = 0; i < 8; ++i)
          #pragma unroll
          for (int j = 0; j < 8; ++j)
            acc[i][j] = fmaf(av[i], bw[j], acc[i][j]);
      }
    }

    // epilogue: score = dot + bias (separate RNE add, like np matmul + bias)
    float bv[8];
    #pragma unroll
    for (int j = 0; j < 8; ++j) bv[j] = __fmul_rn(0.1f, imp[n_base + tn * 8 + j]);

    int need = 0;
    #pragma unroll
    for (int i = 0; i < 8; ++i) {
      float thr = tthr[tm * 8 + i];
      #pragma unroll
      for (int j = 0; j < 8; ++j) {
        float s = __fadd_rn(acc[i][j], bv[j]);
        need |= (s > thr) ? 1 : 0;
      }
    }
    unsigned long long mask = __ballot(need);
    while (mask) {                       // serialized inserts, ascending n:
      int cur = __ffsll(mask) - 1;       // stable tie-break (earlier idx wins)
      mask &= mask - 1;                  // == lax.top_k semantics
      if (lane == cur) {
        #pragma unroll
        for (int i = 0; i < 8; ++i) {
          int r = tm * 8 + i;
          #pragma unroll
          for (int j = 0; j < 8; ++j) {
            float s = __fadd_rn(acc[i][j], bv[j]);
            if (s > tthr[r]) {           // strictly greater only
              int p = TOPK - 1;
              while (p > 0 && tval[r][p-1] < s) {
                tval[r][p] = tval[r][p-1];
                tidx[r][p] = tidx[r][p-1];
                --p;
              }
              tval[r][p] = s;
              tidx[r][p] = n_base + tn * 8 + j;
              tthr[r] = tval[r][TOPK-1];
            }
          }
        }
      }
    }
  }

  __syncthreads();

  // ---- per-row softmax (np order) + f32 stores (bf16-RNE prequantized) ---
  if (tid < MBLK) {
    float v[TOPK]; int id[TOPK];
    #pragma unroll
    for (int j = 0; j < TOPK; ++j) { v[j] = tval[tid][j]; id[j] = tidx[tid][j]; }
    float mx = v[0];                     // sorted desc -> max first
    float e[TOPK];
    #pragma unroll
    for (int j = 0; j < TOPK; ++j) e[j] = expf(__fadd_rn(v[j], -mx));
    // np pairwise sum for n=8: ((e0+e1)+(e2+e3))+((e4+e5)+(e6+e7))
    float sum = __fadd_rn(
        __fadd_rn(__fadd_rn(e[0], e[1]), __fadd_rn(e[2], e[3])),
        __fadd_rn(__fadd_rn(e[4], e[5]), __fadd_rn(e[6], e[7])));
    const size_t SEC  = (size_t)M * TOPK;            // 131072 f32 slots
    const size_t base = (size_t)(m_base + tid) * TOPK;
    #pragma unroll
    for (int j = 0; j < TOPK; ++j) {
      out[base + j]         = bf16_rne_f32((float)id[j]);                 // idx
      out[SEC + base + j]   = bf16_rne_f32(v[j]);                         // score
      out[2*SEC + base + j] = bf16_rne_f32(__fdiv_rn(e[j], sum));         // alpha
    }
  }
}

// ---------------- host ---------------------------------------------------
extern "C" void kernel_launch(void* const* d_in, const int* in_sizes, int n_in,
                              void* d_out, int out_size, void* d_ws, size_t ws_size,
                              hipStream_t stream) {
  const float* T   = (const float*)d_in[0];
  const float* S   = (const float*)d_in[1];
  const float* imp = (const float*)d_in[2];
  int M = in_sizes[0] / KDIM;   // 16384
  int N = in_sizes[1] / KDIM;   // 32768

  float* nt = (float*)d_ws;     // M f32 row norms
  float* ns = nt + M;           // N f32 row norms (196 KB total ws)

  float* out = (float*)d_out;   // f32 output buffer (validated model, R12)

  er_norms<<<(4 * (M + N) + 255) / 256, 256, 0, stream>>>(T, S, nt, ns, M, N);
  er_fused<<<M / MBLK, NTH, 0, stream>>>(T, S, imp, nt, ns, out, M, N);
}